// Round 5
// baseline (566.904 us; speedup 1.0000x reference)
//
#include <hip/hip_runtime.h>

typedef _Float16 half8  __attribute__((ext_vector_type(8)));
typedef _Float16 half4_t __attribute__((ext_vector_type(4)));
typedef float    f32x4  __attribute__((ext_vector_type(4)));

static constexpr int BATCH = 16;
static constexpr int NSEQ  = 2048;
static constexpr int DDIM  = 512;
static constexpr int MROWS = BATCH * NSEQ;   // 32768

// workspace layout (bytes)
static constexpr size_t WT_OFF  = 0;                                      // 1.5MB
static constexpr size_t QKV_OFF = 2u * 1024 * 1024;                       // 96MB
static constexpr size_t VT_OFF  = QKV_OFF + (size_t)3 * MROWS * DDIM * 2; // 32MB (vt; also xh before v_transpose)

// async global->LDS, 16B per lane, dest = uniform base + lane*16
typedef const __attribute__((address_space(1))) void cg_void;
typedef __attribute__((address_space(3))) void lds_void;
__device__ __forceinline__ void gload_lds16(const void* g, void* l) {
    __builtin_amdgcn_global_load_lds((cg_void*)g, (lds_void*)l, 16, 0, 0);
}

// ---------------- K0a: x fp32 -> fp16 ---------------------------------------
__global__ void xconv(const float* __restrict__ x, _Float16* __restrict__ xh) {
    size_t base = ((size_t)blockIdx.x * 256 + threadIdx.x) * 8;
    float4 a = *(const float4*)(x + base);
    float4 b = *(const float4*)(x + base + 4);
    half8 h;
    h[0] = (_Float16)a.x; h[1] = (_Float16)a.y; h[2] = (_Float16)a.z; h[3] = (_Float16)a.w;
    h[4] = (_Float16)b.x; h[5] = (_Float16)b.y; h[6] = (_Float16)b.z; h[7] = (_Float16)b.w;
    *(half8*)(xh + base) = h;
}

// ---------------- K0b: weight fp32 -> fp16, transposed Wt[ng][e] ------------
__global__ void wt_prep(const float* __restrict__ Wq, const float* __restrict__ Wk,
                        const float* __restrict__ Wv, _Float16* __restrict__ wt) {
    int idx = blockIdx.x * 256 + threadIdx.x;   // 1536*512 total
    int ng  = idx >> 9;
    int e   = idx & 511;
    const float* W = (ng < 512) ? Wq : (ng < 1024 ? Wk : Wv);
    wt[idx] = (_Float16)W[e * 512 + (ng & 511)];
}

// ---------------- K1: fused QKV projection GEMM (128x128 tile) ---------------
__global__ __launch_bounds__(256, 2) void qkv_gemm(
        const _Float16* __restrict__ xh, const _Float16* __restrict__ wt,
        const float* __restrict__ bq, const float* __restrict__ bk,
        const float* __restrict__ bv, _Float16* __restrict__ qkv) {
    __shared__ alignas(16) char Asw[128 * 128];
    __shared__ alignas(16) char Bsw[128 * 128];
    const int tid  = threadIdx.x;
    const int lane = tid & 63;
    const int wid  = tid >> 6;
    const int lg = lane >> 4, lm = lane & 15;
    const int wr = wid >> 1, wc = wid & 1;

    const int id = blockIdx.x;
    const int wg = (id & 7) * 384 + (id >> 3);
    const int bm = wg & 255, bn = wg >> 8;
    const int m0 = bm * 128, n0 = bn * 128;
    const int proj = n0 >> 9;
    const float* bias = (proj == 0) ? bq : (proj == 1 ? bk : bv);

    f32x4 acc[4][4] = {};

    const int rloc = (lane >> 3);
    const int p    = lane & 7;

    for (int kk = 0; kk < 512; kk += 64) {
        __syncthreads();
        #pragma unroll
        for (int i = 0; i < 4; ++i) {
            int g = wid * 4 + i;
            int r = g * 8 + rloc;
            gload_lds16(xh + (size_t)(m0 + r) * 512 + kk + ((p ^ (r & 7)) * 8),
                        Asw + g * 1024);
            gload_lds16(wt + (size_t)(n0 + r) * 512 + kk + ((p ^ (r & 7)) * 8),
                        Bsw + g * 1024);
        }
        __syncthreads();
        #pragma unroll
        for (int es = 0; es < 2; ++es) {
            half8 a[4], b[4];
            #pragma unroll
            for (int i = 0; i < 4; ++i) {
                int row = wr * 64 + i * 16 + lm;
                a[i] = *(const half8*)(Asw + row * 128 + (((es * 4 + lg) ^ (row & 7)) * 16));
            }
            #pragma unroll
            for (int j = 0; j < 4; ++j) {
                int row = wc * 64 + j * 16 + lm;
                b[j] = *(const half8*)(Bsw + row * 128 + (((es * 4 + lg) ^ (row & 7)) * 16));
            }
            #pragma unroll
            for (int i = 0; i < 4; ++i)
                #pragma unroll
                for (int j = 0; j < 4; ++j)
                    acc[i][j] = __builtin_amdgcn_mfma_f32_16x16x32_f16(a[i], b[j], acc[i][j], 0, 0, 0);
        }
    }
    const size_t pb = (size_t)proj * MROWS * DDIM;
    #pragma unroll
    for (int i = 0; i < 4; ++i) {
        #pragma unroll
        for (int j = 0; j < 4; ++j) {
            int mg = m0 + wr * 64 + i * 16 + lg * 4;
            int c  = (n0 & 511) + wc * 64 + j * 16 + lm;
            float bb = bias[c];
            #pragma unroll
            for (int r = 0; r < 4; ++r)
                qkv[pb + (size_t)(mg + r) * DDIM + c] = (_Float16)(acc[i][j][r] + bb);
        }
    }
}

// ---------------- K2: v[b][n][e] -> vt[b][e][n] ------------------------------
__global__ void v_transpose(const _Float16* __restrict__ v, _Float16* __restrict__ vt) {
    __shared__ alignas(16) _Float16 T[64][72];
    const int b = blockIdx.z;
    const int n0 = blockIdx.x * 64, e0 = blockIdx.y * 64;
    const int tid = threadIdx.x;
    #pragma unroll
    for (int i = 0; i < 2; ++i) {
        int c = tid + i * 256;
        int row = c >> 3, o = c & 7;
        int4 val = *(const int4*)(v + ((size_t)b * NSEQ + n0 + row) * 512 + e0 + o * 8);
        *(int4*)&T[row][o * 8] = val;
    }
    __syncthreads();
    #pragma unroll
    for (int i = 0; i < 2; ++i) {
        int c = tid + i * 256;
        int erow = c >> 3, o = c & 7;
        _Float16 tmp[8];
        #pragma unroll
        for (int j = 0; j < 8; ++j) tmp[j] = T[o * 8 + j][erow];
        *(int4*)(vt + (size_t)b * 512 * NSEQ + (size_t)(e0 + erow) * NSEQ + n0 + o * 8) =
            *(int4*)tmp;
    }
}

// ---------------- K3: flash attention, e-split PV, single-buffered LDS -------
// block = 64 q-rows, 4 waves. Per tile: waves do QK+softmax on own 16 rows,
// publish P[64][32]+sc[64] to LDS, then each wave does PV for ALL 64 rows on
// its private 128 e-columns. K staged in [beta, alpha) window, V in [alpha, beta).
__global__ __launch_bounds__(256, 2) void attn(
        const _Float16* __restrict__ q, const _Float16* __restrict__ k,
        const _Float16* __restrict__ vt, float* __restrict__ out) {
    __shared__ alignas(16) char Ks[32 * 1024];   // [key][512 f16], granule ^ (key&7)
    __shared__ alignas(16) char Vs[32 * 1024];   // [e][32 f16],   granule ^ ((e>>1)&3)
    __shared__ alignas(16) char Ps[64 * 64];     // [row][32 f16], granule ^ ((row>>2)&3)
    __shared__ alignas(16) float scA[64];

    const int tid = threadIdx.x, lane = tid & 63, wid = tid >> 6;   // wid 0..3
    const int lg = lane >> 4, lm = lane & 15;

    // XCD-aware mapping: same-XCD blocks (id&7) share 2 batches
    const int id = blockIdx.x;                  // 512 blocks
    const int b  = (id & 7) * 2 + (id >> 8);
    const int n0 = ((id >> 3) & 31) * 64;

    // Q fragments: rows = n0 + wid*16 + lm
    const _Float16* qrow = q + ((size_t)(b * NSEQ + n0 + wid * 16 + lm)) * 512;
    half8 qf[16];
    #pragma unroll
    for (int es = 0; es < 16; ++es)
        qf[es] = *(const half8*)(qrow + es * 32 + lg * 8);

    f32x4 o[4][8] = {};    // [row-group m][e-group eg]; e = wid*128 + eg*16 + lm
    float m_r[4], l_r[4];
    #pragma unroll
    for (int r = 0; r < 4; ++r) { m_r[r] = -__builtin_inff(); l_r[r] = 0.f; }

    const _Float16* kb  = k  + (size_t)b * NSEQ * 512;
    const _Float16* vtb = vt + (size_t)b * 512 * NSEQ;

    // staging offsets: chunk i covers 1KB; R = wid*8+i
    int koff[8], voff[8];
    #pragma unroll
    for (int i = 0; i < 8; ++i) {
        int R = wid * 8 + i;
        koff[i] = R * 512 + ((lane ^ (R & 7)) * 8);
        voff[i] = (R * 16 + (lane >> 2)) * NSEQ + (((lane & 3) ^ ((lane >> 3) & 3)) * 8);
    }

    // prologue: stage K tile 0
    #pragma unroll
    for (int i = 0; i < 8; ++i)
        gload_lds16(kb + koff[i], Ks + (wid * 8 + i) * 1024);

    for (int t = 0; t < 64; ++t) {
        __syncthreads();    // alpha: K[t] resident; Vs/Ps free for reuse
        {   // stage V[t] (consumed after beta)
            const _Float16* vs = vtb + t * 32;
            #pragma unroll
            for (int i = 0; i < 8; ++i)
                gload_lds16(vs + voff[i], Vs + (wid * 8 + i) * 1024);
        }

        // QK^T on own 16 rows
        f32x4 s0 = {}, s1 = {};
        #pragma unroll
        for (int es = 0; es < 16; ++es) {
            const int off = es * 64 + lg * 16;
            half8 k0 = *(const half8*)(Ks + lm * 1024 + (off ^ ((lm & 7) << 4)));
            half8 k1 = *(const half8*)(Ks + (lm + 16) * 1024 + (off ^ ((lm & 7) << 4)));
            s0 = __builtin_amdgcn_mfma_f32_16x16x32_f16(qf[es], k0, s0, 0, 0, 0);
            s1 = __builtin_amdgcn_mfma_f32_16x16x32_f16(qf[es], k1, s1, 0, 0, 0);
        }

        // online softmax (row = wid*16 + lg*4 + r; keys across lm)
        float sc[4], p0[4], p1[4];
        #pragma unroll
        for (int r = 0; r < 4; ++r) {
            float tm = fmaxf(s0[r], s1[r]);
            #pragma unroll
            for (int d = 1; d < 16; d <<= 1) tm = fmaxf(tm, __shfl_xor(tm, d));
            float mn = fmaxf(m_r[r], tm);
            sc[r] = __expf(m_r[r] - mn);
            p0[r] = __expf(s0[r] - mn);
            p1[r] = __expf(s1[r] - mn);
            float rsum = p0[r] + p1[r];
            #pragma unroll
            for (int d = 1; d < 16; d <<= 1) rsum += __shfl_xor(rsum, d);
            l_r[r] = l_r[r] * sc[r] + rsum;
            m_r[r] = mn;
        }

        // publish P (swizzled granule = g ^ ((row>>2)&3); here (row>>2)&3 == lg)
        #pragma unroll
        for (int r = 0; r < 4; ++r) {
            int row = wid * 16 + lg * 4 + r;
            *(_Float16*)(Ps + row * 64 + (((lm >> 3) ^ lg) << 4) + (lm & 7) * 2) = (_Float16)p0[r];
            *(_Float16*)(Ps + row * 64 + (((2 + (lm >> 3)) ^ lg) << 4) + (lm & 7) * 2) = (_Float16)p1[r];
        }
        if (lm == 0) {
            f32x4 scv; scv[0] = sc[0]; scv[1] = sc[1]; scv[2] = sc[2]; scv[3] = sc[3];
            *(f32x4*)&scA[wid * 16 + lg * 4] = scv;
        }

        __syncthreads();    // beta: P, scA, V[t] ready; Ks consumed by all waves

        if (t < 63) {       // stage K[t+1] (consumed after next alpha)
            const _Float16* ks2 = kb + (size_t)(t + 1) * (32 * 512);
            #pragma unroll
            for (int i = 0; i < 8; ++i)
                gload_lds16(ks2 + koff[i], Ks + (wid * 8 + i) * 1024);
        }

        // rescale O (all 64 rows, own e-slice) with shared sc
        #pragma unroll
        for (int m = 0; m < 4; ++m) {
            f32x4 scv = *(const f32x4*)&scA[m * 16 + lg * 4];
            #pragma unroll
            for (int eg = 0; eg < 8; ++eg)
                #pragma unroll
                for (int r = 0; r < 4; ++r) o[m][eg][r] *= scv[r];
        }

        // PV: rows = all 64, e-cols = wid*128 + eg*16 + lm
        half8 vf[8];
        #pragma unroll
        for (int eg = 0; eg < 8; ++eg) {
            int e = wid * 128 + eg * 16 + lm;
            vf[eg] = *(const half8*)(Vs + e * 64 + ((lg ^ ((lm >> 1) & 3)) << 4));
        }
        #pragma unroll
        for (int m = 0; m < 4; ++m) {
            int row = m * 16 + lm;
            half8 pf = *(const half8*)(Ps + row * 64 + ((lg ^ ((lm >> 2) & 3)) << 4));
            #pragma unroll
            for (int eg = 0; eg < 8; ++eg)
                o[m][eg] = __builtin_amdgcn_mfma_f32_16x16x32_f16(pf, vf[eg], o[m][eg], 0, 0, 0);
        }
    }

    // epilogue: share denominators, normalize, store fp32
    __syncthreads();
    if (lm == 0) {
        f32x4 lv; lv[0] = l_r[0]; lv[1] = l_r[1]; lv[2] = l_r[2]; lv[3] = l_r[3];
        *(f32x4*)&scA[wid * 16 + lg * 4] = lv;
    }
    __syncthreads();
    #pragma unroll
    for (int m = 0; m < 4; ++m) {
        f32x4 lv = *(const f32x4*)&scA[m * 16 + lg * 4];
        float inv[4];
        #pragma unroll
        for (int r = 0; r < 4; ++r) inv[r] = __builtin_amdgcn_rcpf(lv[r]);
        #pragma unroll
        for (int eg = 0; eg < 8; ++eg) {
            #pragma unroll
            for (int r = 0; r < 4; ++r) {
                out[((size_t)(b * NSEQ + n0 + m * 16 + lg * 4 + r)) * 512
                    + wid * 128 + eg * 16 + lm] = o[m][eg][r] * inv[r];
            }
        }
    }
}

// ---------------- launcher ---------------------------------------------------
extern "C" void kernel_launch(void* const* d_in, const int* in_sizes, int n_in,
                              void* d_out, int out_size, void* d_ws, size_t ws_size,
                              hipStream_t stream) {
    const float* x  = (const float*)d_in[0];
    const float* Wq = (const float*)d_in[1];
    const float* bq = (const float*)d_in[2];
    const float* Wk = (const float*)d_in[3];
    const float* bk = (const float*)d_in[4];
    const float* Wv = (const float*)d_in[5];
    const float* bv = (const float*)d_in[6];
    float* out = (float*)d_out;
    char* ws = (char*)d_ws;

    _Float16* wt   = (_Float16*)(ws + WT_OFF);
    _Float16* qkv  = (_Float16*)(ws + QKV_OFF);
    _Float16* qbuf = qkv;
    _Float16* kbuf = qkv + (size_t)1 * MROWS * DDIM;
    _Float16* vbuf = qkv + (size_t)2 * MROWS * DDIM;
    _Float16* vt   = (_Float16*)(ws + VT_OFF);
    _Float16* xh   = (_Float16*)(ws + VT_OFF);   // aliased: xh dead before v_transpose writes vt

    xconv<<<8192, 256, 0, stream>>>(x, xh);
    wt_prep<<<(1536 * 512) / 256, 256, 0, stream>>>(Wq, Wk, Wv, wt);
    qkv_gemm<<<3072, 256, 0, stream>>>(xh, wt, bq, bk, bv, qkv);
    v_transpose<<<dim3(NSEQ / 64, DDIM / 64, BATCH), 256, 0, stream>>>(vbuf, vt);
    attn<<<512, 256, 0, stream>>>(qbuf, kbuf, vt, out);
}

// Round 6
// 528.901 us; speedup vs baseline: 1.0719x; 1.0719x over previous
//
#include <hip/hip_runtime.h>

typedef _Float16 half8  __attribute__((ext_vector_type(8)));
typedef _Float16 half4_t __attribute__((ext_vector_type(4)));
typedef float    f32x4  __attribute__((ext_vector_type(4)));

static constexpr int BATCH = 16;
static constexpr int NSEQ  = 2048;
static constexpr int DDIM  = 512;
static constexpr int MROWS = BATCH * NSEQ;   // 32768

// workspace layout (bytes)
static constexpr size_t WT_OFF  = 0;                                      // 1.5MB
static constexpr size_t QKV_OFF = 2u * 1024 * 1024;                       // 96MB
static constexpr size_t VT_OFF  = QKV_OFF + (size_t)3 * MROWS * DDIM * 2; // 32MB (vt; also xh before v_transpose)

// async global->LDS, 16B per lane, dest = uniform base + lane*16
typedef const __attribute__((address_space(1))) void cg_void;
typedef __attribute__((address_space(3))) void lds_void;
__device__ __forceinline__ void gload_lds16(const void* g, void* l) {
    __builtin_amdgcn_global_load_lds((cg_void*)g, (lds_void*)l, 16, 0, 0);
}

// ---------------- K0a: x fp32 -> fp16 ---------------------------------------
__global__ void xconv(const float* __restrict__ x, _Float16* __restrict__ xh) {
    size_t base = ((size_t)blockIdx.x * 256 + threadIdx.x) * 8;
    float4 a = *(const float4*)(x + base);
    float4 b = *(const float4*)(x + base + 4);
    half8 h;
    h[0] = (_Float16)a.x; h[1] = (_Float16)a.y; h[2] = (_Float16)a.z; h[3] = (_Float16)a.w;
    h[4] = (_Float16)b.x; h[5] = (_Float16)b.y; h[6] = (_Float16)b.z; h[7] = (_Float16)b.w;
    *(half8*)(xh + base) = h;
}

// ---------------- K0b: weight fp32 -> fp16, transposed Wt[ng][e] ------------
__global__ void wt_prep(const float* __restrict__ Wq, const float* __restrict__ Wk,
                        const float* __restrict__ Wv, _Float16* __restrict__ wt) {
    int idx = blockIdx.x * 256 + threadIdx.x;   // 1536*512 total
    int ng  = idx >> 9;
    int e   = idx & 511;
    const float* W = (ng < 512) ? Wq : (ng < 1024 ? Wk : Wv);
    wt[idx] = (_Float16)W[e * 512 + (ng & 511)];
}

// ---------------- K1: fused QKV projection GEMM (128x128 tile) ---------------
__global__ __launch_bounds__(256, 2) void qkv_gemm(
        const _Float16* __restrict__ xh, const _Float16* __restrict__ wt,
        const float* __restrict__ bq, const float* __restrict__ bk,
        const float* __restrict__ bv, _Float16* __restrict__ qkv) {
    __shared__ alignas(16) char Asw[128 * 128];
    __shared__ alignas(16) char Bsw[128 * 128];
    const int tid  = threadIdx.x;
    const int lane = tid & 63;
    const int wid  = tid >> 6;
    const int lg = lane >> 4, lm = lane & 15;
    const int wr = wid >> 1, wc = wid & 1;

    const int id = blockIdx.x;
    const int wg = (id & 7) * 384 + (id >> 3);
    const int bm = wg & 255, bn = wg >> 8;
    const int m0 = bm * 128, n0 = bn * 128;
    const int proj = n0 >> 9;
    const float* bias = (proj == 0) ? bq : (proj == 1 ? bk : bv);

    f32x4 acc[4][4] = {};

    const int rloc = (lane >> 3);
    const int p    = lane & 7;

    for (int kk = 0; kk < 512; kk += 64) {
        __syncthreads();
        #pragma unroll
        for (int i = 0; i < 4; ++i) {
            int g = wid * 4 + i;
            int r = g * 8 + rloc;
            gload_lds16(xh + (size_t)(m0 + r) * 512 + kk + ((p ^ (r & 7)) * 8),
                        Asw + g * 1024);
            gload_lds16(wt + (size_t)(n0 + r) * 512 + kk + ((p ^ (r & 7)) * 8),
                        Bsw + g * 1024);
        }
        __syncthreads();
        #pragma unroll
        for (int es = 0; es < 2; ++es) {
            half8 a[4], b[4];
            #pragma unroll
            for (int i = 0; i < 4; ++i) {
                int row = wr * 64 + i * 16 + lm;
                a[i] = *(const half8*)(Asw + row * 128 + (((es * 4 + lg) ^ (row & 7)) * 16));
            }
            #pragma unroll
            for (int j = 0; j < 4; ++j) {
                int row = wc * 64 + j * 16 + lm;
                b[j] = *(const half8*)(Bsw + row * 128 + (((es * 4 + lg) ^ (row & 7)) * 16));
            }
            #pragma unroll
            for (int i = 0; i < 4; ++i)
                #pragma unroll
                for (int j = 0; j < 4; ++j)
                    acc[i][j] = __builtin_amdgcn_mfma_f32_16x16x32_f16(a[i], b[j], acc[i][j], 0, 0, 0);
        }
    }
    const size_t pb = (size_t)proj * MROWS * DDIM;
    #pragma unroll
    for (int i = 0; i < 4; ++i) {
        #pragma unroll
        for (int j = 0; j < 4; ++j) {
            int mg = m0 + wr * 64 + i * 16 + lg * 4;
            int c  = (n0 & 511) + wc * 64 + j * 16 + lm;
            float bb = bias[c];
            #pragma unroll
            for (int r = 0; r < 4; ++r)
                qkv[pb + (size_t)(mg + r) * DDIM + c] = (_Float16)(acc[i][j][r] + bb);
        }
    }
}

// ---------------- K2: v[b][n][e] -> vt[b][e][n] ------------------------------
__global__ void v_transpose(const _Float16* __restrict__ v, _Float16* __restrict__ vt) {
    __shared__ alignas(16) _Float16 T[64][72];
    const int b = blockIdx.z;
    const int n0 = blockIdx.x * 64, e0 = blockIdx.y * 64;
    const int tid = threadIdx.x;
    #pragma unroll
    for (int i = 0; i < 2; ++i) {
        int c = tid + i * 256;
        int row = c >> 3, o = c & 7;
        int4 val = *(const int4*)(v + ((size_t)b * NSEQ + n0 + row) * 512 + e0 + o * 8);
        *(int4*)&T[row][o * 8] = val;
    }
    __syncthreads();
    #pragma unroll
    for (int i = 0; i < 2; ++i) {
        int c = tid + i * 256;
        int erow = c >> 3, o = c & 7;
        _Float16 tmp[8];
        #pragma unroll
        for (int j = 0; j < 8; ++j) tmp[j] = T[o * 8 + j][erow];
        *(int4*)(vt + (size_t)b * 512 * NSEQ + (size_t)(e0 + erow) * NSEQ + n0 + o * 8) =
            *(int4*)tmp;
    }
}

// ---------------- K3: flash attention, counted-vmcnt pipeline (T3+T4+T5+T13) -
// block = 128 q-rows (8 waves x 16), 64 K-tiles of 32 keys.
// K,V double-buffered; raw s_barrier + s_waitcnt vmcnt(8); stage t+2 after
// compute; vmcnt never drains to 0 in steady state.
__global__ __launch_bounds__(512, 2) void attn(
        const _Float16* __restrict__ q, const _Float16* __restrict__ k,
        const _Float16* __restrict__ vt, float* __restrict__ out) {
    __shared__ alignas(16) char KsB[2 * 32768];          // [buf][key][512 f16], granule ^ (key&7)
    __shared__ alignas(16) char VsB[2 * 32768];          // [buf][e][32 f16],   granule ^ ((e>>1)&3)
    __shared__ alignas(16) _Float16 Pl[8][16][40];       // per-wave P relayout

    const int tid = threadIdx.x, lane = tid & 63, wid = tid >> 6;   // wid 0..7
    const int lg = lane >> 4, lm = lane & 15;

    // XCD-aware: blocks of batch b land on XCD (b&7) -> K/V L2-resident
    const int id = blockIdx.x;                  // 256 blocks
    const int b  = (id & 7) | ((id >> 7) << 3);
    const int n0 = ((id >> 3) & 15) * 128;

    // Q fragments: rows = n0 + wid*16 + lm
    const _Float16* qrow = q + ((size_t)(b * NSEQ + n0 + wid * 16 + lm)) * 512;
    half8 qf[16];
    #pragma unroll
    for (int es = 0; es < 16; ++es)
        qf[es] = *(const half8*)(qrow + es * 32 + lg * 8);

    f32x4 o[32] = {};
    float m_r[4], l_r[4];
    #pragma unroll
    for (int r = 0; r < 4; ++r) { m_r[r] = -__builtin_inff(); l_r[r] = 0.f; }

    const _Float16* kb  = k  + (size_t)b * NSEQ * 512;
    const _Float16* vtb = vt + (size_t)b * 512 * NSEQ;

    // staging offsets: chunk i covers 1KB; R = wid*4+i (8 waves x 4 = 32 chunks)
    int koff[4], voff[4];
    #pragma unroll
    for (int i = 0; i < 4; ++i) {
        int R = wid * 4 + i;
        koff[i] = R * 512 + ((lane ^ (R & 7)) * 8);
        voff[i] = (R * 16 + (lane >> 2)) * NSEQ + (((lane & 3) ^ ((lane >> 3) & 3)) * 8);
    }

    auto STAGE = [&](int tt, int bb) {
        const _Float16* ks = kb + (size_t)tt * (32 * 512);
        const _Float16* vs = vtb + (size_t)tt * 32;
        #pragma unroll
        for (int i = 0; i < 4; ++i) {
            gload_lds16(ks + koff[i], KsB + bb * 32768 + (wid * 4 + i) * 1024);
            gload_lds16(vs + voff[i], VsB + bb * 32768 + (wid * 4 + i) * 1024);
        }
    };

    // prologue: 16 loads in flight (tiles 0,1)
    STAGE(0, 0);
    STAGE(1, 1);

    for (int t = 0; t < 64; ++t) {
        // wait for tile t's 8 loads; keep tile t+1's 8 in flight
        if (t < 62) asm volatile("s_waitcnt vmcnt(8)" ::: "memory");
        else        asm volatile("s_waitcnt vmcnt(0)" ::: "memory");
        __builtin_amdgcn_s_barrier();     // all waves' tile-t loads complete

        const char* Ksb = KsB + (t & 1) * 32768;
        const char* Vsb = VsB + (t & 1) * 32768;

        // QK^T
        f32x4 s0 = {}, s1 = {};
        __builtin_amdgcn_s_setprio(1);
        #pragma unroll
        for (int es = 0; es < 16; ++es) {
            const int off = es * 64 + lg * 16;
            half8 k0 = *(const half8*)(Ksb + lm * 1024 + (off ^ ((lm & 7) << 4)));
            half8 k1 = *(const half8*)(Ksb + (lm + 16) * 1024 + (off ^ ((lm & 7) << 4)));
            s0 = __builtin_amdgcn_mfma_f32_16x16x32_f16(qf[es], k0, s0, 0, 0, 0);
            s1 = __builtin_amdgcn_mfma_f32_16x16x32_f16(qf[es], k1, s1, 0, 0, 0);
        }
        __builtin_amdgcn_s_setprio(0);

        // online softmax with defer-max (THR=8): skip O-rescale when max static
        float sc[4], p0[4], p1[4];
        bool resc = false;
        #pragma unroll
        for (int r = 0; r < 4; ++r) {
            float tm = fmaxf(s0[r], s1[r]);
            #pragma unroll
            for (int d = 1; d < 16; d <<= 1) tm = fmaxf(tm, __shfl_xor(tm, d));
            float mn = fmaxf(m_r[r], tm);
            float use_m;
            if (mn - m_r[r] <= 8.f) {       // deferred: keep old max, P <= e^8 (f16-safe)
                use_m = m_r[r]; sc[r] = 1.f;
            } else {
                use_m = mn; sc[r] = __expf(m_r[r] - mn); m_r[r] = mn; resc = true;
            }
            p0[r] = __expf(s0[r] - use_m);
            p1[r] = __expf(s1[r] - use_m);
            float rsum = p0[r] + p1[r];
            #pragma unroll
            for (int d = 1; d < 16; d <<= 1) rsum += __shfl_xor(rsum, d);
            l_r[r] = l_r[r] * sc[r] + rsum;
        }

        // P relayout via per-wave LDS (C-layout write, A-fragment read)
        #pragma unroll
        for (int r = 0; r < 4; ++r) {
            Pl[wid][lg * 4 + r][lm]      = (_Float16)p0[r];
            Pl[wid][lg * 4 + r][lm + 16] = (_Float16)p1[r];
        }
        half8 pf = *(const half8*)&Pl[wid][lm][lg * 8];

        if (__any((int)resc)) {
            #pragma unroll
            for (int eg = 0; eg < 32; ++eg)
                #pragma unroll
                for (int r = 0; r < 4; ++r) o[eg][r] *= sc[r];
        }

        // PV
        __builtin_amdgcn_s_setprio(1);
        #pragma unroll
        for (int eg = 0; eg < 32; ++eg) {
            int e = eg * 16 + lm;
            half8 vf = *(const half8*)(Vsb + e * 64 + ((lg ^ ((lm >> 1) & 3)) << 4));
            o[eg] = __builtin_amdgcn_mfma_f32_16x16x32_f16(pf, vf, o[eg], 0, 0, 0);
        }
        __builtin_amdgcn_s_setprio(0);

        __builtin_amdgcn_s_barrier();     // all waves done reading buf (t&1)
        asm volatile("" ::: "memory");
        if (t + 2 < 64) STAGE(t + 2, t & 1);   // overwrite buf (t&1), lands before wait at t+2
    }

    // epilogue: normalize, store fp32
    float inv[4];
    #pragma unroll
    for (int r = 0; r < 4; ++r) inv[r] = 1.f / l_r[r];
    float* ob = out + ((size_t)(b * NSEQ + n0 + wid * 16 + lg * 4)) * 512;
    #pragma unroll
    for (int eg = 0; eg < 32; ++eg)
        #pragma unroll
        for (int r = 0; r < 4; ++r)
            ob[(size_t)r * 512 + eg * 16 + lm] = o[eg][r] * inv[r];
}

// ---------------- launcher ---------------------------------------------------
extern "C" void kernel_launch(void* const* d_in, const int* in_sizes, int n_in,
                              void* d_out, int out_size, void* d_ws, size_t ws_size,
                              hipStream_t stream) {
    const float* x  = (const float*)d_in[0];
    const float* Wq = (const float*)d_in[1];
    const float* bq = (const float*)d_in[2];
    const float* Wk = (const float*)d_in[3];
    const float* bk = (const float*)d_in[4];
    const float* Wv = (const float*)d_in[5];
    const float* bv = (const float*)d_in[6];
    float* out = (float*)d_out;
    char* ws = (char*)d_ws;

    _Float16* wt   = (_Float16*)(ws + WT_OFF);
    _Float16* qkv  = (_Float16*)(ws + QKV_OFF);
    _Float16* qbuf = qkv;
    _Float16* kbuf = qkv + (size_t)1 * MROWS * DDIM;
    _Float16* vbuf = qkv + (size_t)2 * MROWS * DDIM;
    _Float16* vt   = (_Float16*)(ws + VT_OFF);
    _Float16* xh   = (_Float16*)(ws + VT_OFF);   // aliased: xh dead before v_transpose writes vt

    xconv<<<8192, 256, 0, stream>>>(x, xh);
    wt_prep<<<(1536 * 512) / 256, 256, 0, stream>>>(Wq, Wk, Wv, wt);
    qkv_gemm<<<3072, 256, 0, stream>>>(xh, wt, bq, bk, bv, qkv);
    v_transpose<<<dim3(NSEQ / 64, DDIM / 64, BATCH), 256, 0, stream>>>(vbuf, vt);
    attn<<<256, 512, 0, stream>>>(qbuf, kbuf, vt, out);
}

// Round 7
// 440.628 us; speedup vs baseline: 1.2866x; 1.2003x over previous
//
#include <hip/hip_runtime.h>

typedef _Float16 half8  __attribute__((ext_vector_type(8)));
typedef _Float16 half4_t __attribute__((ext_vector_type(4)));
typedef float    f32x4  __attribute__((ext_vector_type(4)));

static constexpr int BATCH = 16;
static constexpr int NSEQ  = 2048;
static constexpr int DDIM  = 512;
static constexpr int MROWS = BATCH * NSEQ;   // 32768

// workspace layout (bytes)
static constexpr size_t WT_OFF  = 0;                                      // 1.5MB
static constexpr size_t QKV_OFF = 2u * 1024 * 1024;                       // 96MB
static constexpr size_t VT_OFF  = QKV_OFF + (size_t)3 * MROWS * DDIM * 2; // 32MB (vt; also xh before v_transpose)

// async global->LDS, 16B per lane, dest = uniform base + lane*16
typedef const __attribute__((address_space(1))) void cg_void;
typedef __attribute__((address_space(3))) void lds_void;
__device__ __forceinline__ void gload_lds16(const void* g, void* l) {
    __builtin_amdgcn_global_load_lds((cg_void*)g, (lds_void*)l, 16, 0, 0);
}

// ---------------- K0a: x fp32 -> fp16 ---------------------------------------
__global__ void xconv(const float* __restrict__ x, _Float16* __restrict__ xh) {
    size_t base = ((size_t)blockIdx.x * 256 + threadIdx.x) * 8;
    float4 a = *(const float4*)(x + base);
    float4 b = *(const float4*)(x + base + 4);
    half8 h;
    h[0] = (_Float16)a.x; h[1] = (_Float16)a.y; h[2] = (_Float16)a.z; h[3] = (_Float16)a.w;
    h[4] = (_Float16)b.x; h[5] = (_Float16)b.y; h[6] = (_Float16)b.z; h[7] = (_Float16)b.w;
    *(half8*)(xh + base) = h;
}

// ---------------- K0b: weight fp32 -> fp16, transposed Wt[ng][e] ------------
__global__ void wt_prep(const float* __restrict__ Wq, const float* __restrict__ Wk,
                        const float* __restrict__ Wv, _Float16* __restrict__ wt) {
    int idx = blockIdx.x * 256 + threadIdx.x;   // 1536*512 total
    int ng  = idx >> 9;
    int e   = idx & 511;
    const float* W = (ng < 512) ? Wq : (ng < 1024 ? Wk : Wv);
    wt[idx] = (_Float16)W[e * 512 + (ng & 511)];
}

// ---------------- K1: fused QKV projection GEMM (128x128, dbuf, 1 barrier) --
__global__ __launch_bounds__(256, 2) void qkv_gemm(
        const _Float16* __restrict__ xh, const _Float16* __restrict__ wt,
        const float* __restrict__ bq, const float* __restrict__ bk,
        const float* __restrict__ bv, _Float16* __restrict__ qkv) {
    __shared__ alignas(16) char Asw[2][128 * 128];   // 2 x 16KB
    __shared__ alignas(16) char Bsw[2][128 * 128];
    const int tid  = threadIdx.x;
    const int lane = tid & 63;
    const int wid  = tid >> 6;
    const int lg = lane >> 4, lm = lane & 15;
    const int wr = wid >> 1, wc = wid & 1;

    const int id = blockIdx.x;
    const int wg = (id & 7) * 384 + (id >> 3);
    const int bm = wg & 255, bn = wg >> 8;
    const int m0 = bm * 128, n0 = bn * 128;
    const int proj = n0 >> 9;
    const float* bias = (proj == 0) ? bq : (proj == 1 ? bk : bv);

    f32x4 acc[4][4] = {};

    const int rloc = (lane >> 3);
    const int p    = lane & 7;

    auto STAGE = [&](int kk, int bb) {
        #pragma unroll
        for (int i = 0; i < 4; ++i) {
            int g = wid * 4 + i;
            int r = g * 8 + rloc;
            gload_lds16(xh + (size_t)(m0 + r) * 512 + kk + ((p ^ (r & 7)) * 8),
                        Asw[bb] + g * 1024);
            gload_lds16(wt + (size_t)(n0 + r) * 512 + kk + ((p ^ (r & 7)) * 8),
                        Bsw[bb] + g * 1024);
        }
    };

    STAGE(0, 0);
    for (int ks = 0; ks < 8; ++ks) {
        __syncthreads();                       // drains stage(ks); all waves synced
        if (ks < 7) STAGE((ks + 1) * 64, (ks & 1) ^ 1);
        const char* Ab = Asw[ks & 1];
        const char* Bb = Bsw[ks & 1];
        #pragma unroll
        for (int es = 0; es < 2; ++es) {
            half8 a[4], b[4];
            #pragma unroll
            for (int i = 0; i < 4; ++i) {
                int row = wr * 64 + i * 16 + lm;
                a[i] = *(const half8*)(Ab + row * 128 + (((es * 4 + lg) ^ (row & 7)) * 16));
            }
            #pragma unroll
            for (int j = 0; j < 4; ++j) {
                int row = wc * 64 + j * 16 + lm;
                b[j] = *(const half8*)(Bb + row * 128 + (((es * 4 + lg) ^ (row & 7)) * 16));
            }
            #pragma unroll
            for (int i = 0; i < 4; ++i)
                #pragma unroll
                for (int j = 0; j < 4; ++j)
                    acc[i][j] = __builtin_amdgcn_mfma_f32_16x16x32_f16(a[i], b[j], acc[i][j], 0, 0, 0);
        }
    }
    const size_t pb = (size_t)proj * MROWS * DDIM;
    #pragma unroll
    for (int i = 0; i < 4; ++i) {
        #pragma unroll
        for (int j = 0; j < 4; ++j) {
            int mg = m0 + wr * 64 + i * 16 + lg * 4;
            int c  = (n0 & 511) + wc * 64 + j * 16 + lm;
            float bb = bias[c];
            #pragma unroll
            for (int r = 0; r < 4; ++r)
                qkv[pb + (size_t)(mg + r) * DDIM + c] = (_Float16)(acc[i][j][r] + bb);
        }
    }
}

// ---------------- K2: v[b][n][e] -> vt[b][e][n] ------------------------------
__global__ void v_transpose(const _Float16* __restrict__ v, _Float16* __restrict__ vt) {
    __shared__ alignas(16) _Float16 T[64][72];
    const int b = blockIdx.z;
    const int n0 = blockIdx.x * 64, e0 = blockIdx.y * 64;
    const int tid = threadIdx.x;
    #pragma unroll
    for (int i = 0; i < 2; ++i) {
        int c = tid + i * 256;
        int row = c >> 3, o = c & 7;
        int4 val = *(const int4*)(v + ((size_t)b * NSEQ + n0 + row) * 512 + e0 + o * 8);
        *(int4*)&T[row][o * 8] = val;
    }
    __syncthreads();
    #pragma unroll
    for (int i = 0; i < 2; ++i) {
        int c = tid + i * 256;
        int erow = c >> 3, o = c & 7;
        _Float16 tmp[8];
        #pragma unroll
        for (int j = 0; j < 8; ++j) tmp[j] = T[o * 8 + j][erow];
        *(int4*)(vt + (size_t)b * 512 * NSEQ + (size_t)(e0 + erow) * NSEQ + n0 + o * 8) =
            *(int4*)tmp;
    }
}

// ---------------- K3: flash attention, swapped QK^T, dbuf, 1 barrier/tile ----
// block = 128 q-rows (8 waves x 16), 64 K-tiles of 32 keys.
// Swapped QK: s = mfma(K, Q) -> lane holds 8 scores of q-row lm; row-reduce =
// local max + shfl_xor(16,32). Conflict-free packed P-writes. Defer-max (T13).
__global__ __launch_bounds__(512, 2) void attn(
        const _Float16* __restrict__ q, const _Float16* __restrict__ k,
        const _Float16* __restrict__ vt, float* __restrict__ out) {
    __shared__ alignas(16) char KsB[2 * 32768];       // [buf][key][512 f16], granule ^ (key&7)
    __shared__ alignas(16) char VsB[2 * 32768];       // [buf][e][32 f16],   granule ^ ((e>>1)&3)
    __shared__ alignas(16) _Float16 Pl[8][16][48];    // per-wave P relayout (stride 96B)

    const int tid = threadIdx.x, lane = tid & 63, wid = tid >> 6;   // wid 0..7
    const int lg = lane >> 4, lm = lane & 15;

    // XCD-aware: blocks of batch b land on XCD (b&7) -> K/V L2-resident
    const int id = blockIdx.x;                  // 256 blocks
    const int b  = (id & 7) | ((id >> 7) << 3);
    const int n0 = ((id >> 3) & 15) * 128;

    // Q fragments: rows = n0 + wid*16 + lm (also valid as MFMA B-operand: col=lm)
    const _Float16* qrow = q + ((size_t)(b * NSEQ + n0 + wid * 16 + lm)) * 512;
    half8 qf[16];
    #pragma unroll
    for (int es = 0; es < 16; ++es)
        qf[es] = *(const half8*)(qrow + es * 32 + lg * 8);

    f32x4 o[32] = {};
    float m_r = -__builtin_inff(), l_r = 0.f;   // scalar: this lane's q-row = lm

    const _Float16* kb  = k  + (size_t)b * NSEQ * 512;
    const _Float16* vtb = vt + (size_t)b * 512 * NSEQ;

    // staging offsets: chunk i covers 1KB; R = wid*4+i (8 waves x 4 = 32 chunks)
    int koff[4], voff[4];
    #pragma unroll
    for (int i = 0; i < 4; ++i) {
        int R = wid * 4 + i;
        koff[i] = R * 512 + ((lane ^ (R & 7)) * 8);
        voff[i] = (R * 16 + (lane >> 2)) * NSEQ + (((lane & 3) ^ ((lane >> 3) & 3)) * 8);
    }

    auto STAGE = [&](int tt, int bb) {
        const _Float16* ks = kb + (size_t)tt * (32 * 512);
        const _Float16* vs = vtb + (size_t)tt * 32;
        #pragma unroll
        for (int i = 0; i < 4; ++i) {
            gload_lds16(ks + koff[i], KsB + bb * 32768 + (wid * 4 + i) * 1024);
            gload_lds16(vs + voff[i], VsB + bb * 32768 + (wid * 4 + i) * 1024);
        }
    };

    STAGE(0, 0);
    for (int t = 0; t < 64; ++t) {
        __syncthreads();                 // drains stage(t); tile t resident
        if (t < 63) STAGE(t + 1, (t & 1) ^ 1);
        const char* Ksb = KsB + (t & 1) * 32768;
        const char* Vsb = VsB + (t & 1) * 32768;

        // swapped QK^T: s = K x Q -> C[key][qrow]; lane owns q-row lm,
        // keys lg*4+r (s0) and 16+lg*4+r (s1)
        f32x4 s0 = {}, s1 = {};
        #pragma unroll
        for (int es = 0; es < 16; ++es) {
            const int off = es * 64 + lg * 16;
            half8 k0 = *(const half8*)(Ksb + lm * 1024 + (off ^ ((lm & 7) << 4)));
            half8 k1 = *(const half8*)(Ksb + (lm + 16) * 1024 + (off ^ ((lm & 7) << 4)));
            s0 = __builtin_amdgcn_mfma_f32_16x16x32_f16(k0, qf[es], s0, 0, 0, 0);
            s1 = __builtin_amdgcn_mfma_f32_16x16x32_f16(k1, qf[es], s1, 0, 0, 0);
        }

        // lane-local softmax for q-row lm: 8 local scores + 2 shfl
        float tm = fmaxf(fmaxf(fmaxf(s0[0], s0[1]), fmaxf(s0[2], s0[3])),
                         fmaxf(fmaxf(s1[0], s1[1]), fmaxf(s1[2], s1[3])));
        tm = fmaxf(tm, __shfl_xor(tm, 16));
        tm = fmaxf(tm, __shfl_xor(tm, 32));
        float mn = fmaxf(m_r, tm);
        const bool skip = __all((int)(mn - m_r <= 8.f));   // T13 defer-max, wave-uniform
        float use_m, sc;
        if (skip) { use_m = m_r; sc = 1.f; }
        else      { use_m = mn; sc = __expf(m_r - mn); m_r = mn; }

        float p0[4], p1[4];
        #pragma unroll
        for (int r = 0; r < 4; ++r) {
            p0[r] = __expf(s0[r] - use_m);
            p1[r] = __expf(s1[r] - use_m);
        }
        float rsum = (p0[0] + p0[1]) + (p0[2] + p0[3]) +
                     (p1[0] + p1[1]) + (p1[2] + p1[3]);
        rsum += __shfl_xor(rsum, 16);
        rsum += __shfl_xor(rsum, 32);
        l_r = l_r * sc + rsum;

        // packed P write: row = q-row lm, keys lg*4..+3 and 16+lg*4..+3 (b64, conflict-free)
        half4_t h0, h1;
        #pragma unroll
        for (int r = 0; r < 4; ++r) { h0[r] = (_Float16)p0[r]; h1[r] = (_Float16)p1[r]; }
        *(half4_t*)&Pl[wid][lm][lg * 4]      = h0;
        *(half4_t*)&Pl[wid][lm][16 + lg * 4] = h1;
        half8 pf = *(const half8*)&Pl[wid][lm][lg * 8];   // A-frag: P[qrow=lm][k=lg*8..]

        if (!skip) {     // rescale O; factors live at lanes lm = row
            float scq[4];
            #pragma unroll
            for (int r = 0; r < 4; ++r) scq[r] = __shfl(sc, lg * 4 + r);
            #pragma unroll
            for (int eg = 0; eg < 32; ++eg)
                #pragma unroll
                for (int r = 0; r < 4; ++r) o[eg][r] *= scq[r];
        }

        // PV: O[qrow][e] += P x V
        #pragma unroll
        for (int eg = 0; eg < 32; ++eg) {
            int e = eg * 16 + lm;
            half8 vf = *(const half8*)(Vsb + e * 64 + ((lg ^ ((lm >> 1) & 3)) << 4));
            o[eg] = __builtin_amdgcn_mfma_f32_16x16x32_f16(pf, vf, o[eg], 0, 0, 0);
        }
    }

    // epilogue: denominators for output rows lg*4+r live at lanes lm = row
    float inv[4];
    #pragma unroll
    for (int r = 0; r < 4; ++r) inv[r] = 1.f / __shfl(l_r, lg * 4 + r);
    float* ob = out + ((size_t)(b * NSEQ + n0 + wid * 16 + lg * 4)) * 512;
    #pragma unroll
    for (int eg = 0; eg < 32; ++eg)
        #pragma unroll
        for (int r = 0; r < 4; ++r)
            ob[(size_t)r * 512 + eg * 16 + lm] = o[eg][r] * inv[r];
}

// ---------------- launcher ---------------------------------------------------
extern "C" void kernel_launch(void* const* d_in, const int* in_sizes, int n_in,
                              void* d_out, int out_size, void* d_ws, size_t ws_size,
                              hipStream_t stream) {
    const float* x  = (const float*)d_in[0];
    const float* Wq = (const float*)d_in[1];
    const float* bq = (const float*)d_in[2];
    const float* Wk = (const float*)d_in[3];
    const float* bk = (const float*)d_in[4];
    const float* Wv = (const float*)d_in[5];
    const float* bv = (const float*)d_in[6];
    float* out = (float*)d_out;
    char* ws = (char*)d_ws;

    _Float16* wt   = (_Float16*)(ws + WT_OFF);
    _Float16* qkv  = (_Float16*)(ws + QKV_OFF);
    _Float16* qbuf = qkv;
    _Float16* kbuf = qkv + (size_t)1 * MROWS * DDIM;
    _Float16* vbuf = qkv + (size_t)2 * MROWS * DDIM;
    _Float16* vt   = (_Float16*)(ws + VT_OFF);
    _Float16* xh   = (_Float16*)(ws + VT_OFF);   // aliased: xh dead before v_transpose writes vt

    xconv<<<8192, 256, 0, stream>>>(x, xh);
    wt_prep<<<(1536 * 512) / 256, 256, 0, stream>>>(Wq, Wk, Wv, wt);
    qkv_gemm<<<3072, 256, 0, stream>>>(xh, wt, bq, bk, bv, qkv);
    v_transpose<<<dim3(NSEQ / 64, DDIM / 64, BATCH), 256, 0, stream>>>(vbuf, vt);
    attn<<<256, 512, 0, stream>>>(qbuf, kbuf, vt, out);
}